// Round 5
// baseline (150.448 us; speedup 1.0000x reference)
//
#include <hip/hip_runtime.h>
#include <hip/hip_bf16.h>

#define NB 2
#define NN 20000
#define NKN 16          // neighbors per node
#define NC 128          // C_IN
#define NM 9            // M kernels
#define NO 128          // C_OUT
#define NR (NB*NN)      // 40000 rows
#define KK 1152         // NM*NC GEMM reduce dim
#define NPB 16          // nodes per fused block (2 blocks/CU)
#define YS 12           // padded y row stride (floats)
#define YB (NR/64)      // ycalc blocks = 625
#define SROW 2304       // S' row stride bytes
#define PBASE 36864u    // staging region base in smem (16*2304)
#define SMEMB 69632     // 36864 + 8 waves * 4096 -> 2 blocks/CU

typedef short bf16x8 __attribute__((ext_vector_type(8)));
typedef short bf16x4 __attribute__((ext_vector_type(4)));
typedef float f32x4  __attribute__((ext_vector_type(4)));
typedef unsigned short u16x8 __attribute__((ext_vector_type(8)));

typedef __attribute__((address_space(1))) const void gas_void;
typedef __attribute__((address_space(3))) void las_void;

union frg8 { bf16x4 h[2]; bf16x8 v; };

__device__ inline unsigned short bfb(float f) {
    union { __hip_bfloat16 b; unsigned short u; } t;
    t.b = __float2bfloat16(f);
    return t.u;
}

// ---------------- Kernel 1: prep (unchanged; ct-order Wg) ----------------
// y = x·u^T. Wg repack: kk' = ct*144 + m*16 + ci; layout [kk'>>5][o128][kk'&31].
__global__ __launch_bounds__(256) void prep_kernel(const float* __restrict__ x,
                                                   const float* __restrict__ u,
                                                   const float* __restrict__ W,
                                                   float* __restrict__ y,
                                                   __hip_bfloat16* __restrict__ xb,
                                                   __hip_bfloat16* __restrict__ Wg,
                                                   int use_xb) {
    int tid = threadIdx.x;
    if (blockIdx.x < YB) {
        int wave = tid >> 6, lane = tid & 63;
        int lr = lane & 15, quad = lane >> 4;
        int node0 = blockIdx.x * 64 + wave * 16;
        long xbase = (long)(node0 + lr) * NC;

        bf16x8 afr[4];
        #pragma unroll
        for (int kc = 0; kc < 4; kc++) {
            const float* px = x + xbase + kc * 32 + quad * 8;
            float4 a0 = *(const float4*)px;
            float4 a1 = *(const float4*)(px + 4);
            union { bf16x8 v; unsigned short s[8]; __hip_bfloat16 h[8]; } af;
            af.h[0] = __float2bfloat16(a0.x); af.h[1] = __float2bfloat16(a0.y);
            af.h[2] = __float2bfloat16(a0.z); af.h[3] = __float2bfloat16(a0.w);
            af.h[4] = __float2bfloat16(a1.x); af.h[5] = __float2bfloat16(a1.y);
            af.h[6] = __float2bfloat16(a1.z); af.h[7] = __float2bfloat16(a1.w);
            afr[kc] = af.v;
            if (use_xb)
                *(u16x8*)((unsigned short*)xb + xbase + kc * 32 + quad * 8) =
                    *(u16x8*)&af.v;
        }
        int cs = (lr < NM) ? lr : 0;
        float fz = (lr < NM) ? 1.f : 0.f;
        f32x4 acc = (f32x4){0.f, 0.f, 0.f, 0.f};
        #pragma unroll
        for (int kc = 0; kc < 4; kc++) {
            const float* pu = u + cs * NC + kc * 32 + quad * 8;
            float4 b0 = *(const float4*)pu;
            float4 b1 = *(const float4*)(pu + 4);
            union { bf16x8 v; __hip_bfloat16 h[8]; } bf;
            bf.h[0] = __float2bfloat16(b0.x * fz); bf.h[1] = __float2bfloat16(b0.y * fz);
            bf.h[2] = __float2bfloat16(b0.z * fz); bf.h[3] = __float2bfloat16(b0.w * fz);
            bf.h[4] = __float2bfloat16(b1.x * fz); bf.h[5] = __float2bfloat16(b1.y * fz);
            bf.h[6] = __float2bfloat16(b1.z * fz); bf.h[7] = __float2bfloat16(b1.w * fz);
            acc = __builtin_amdgcn_mfma_f32_16x16x32_bf16(afr[kc], bf.v, acc, 0, 0, 0);
        }
        if (lr < NM) {
            #pragma unroll
            for (int r = 0; r < 4; r++)
                y[(long)(node0 + quad * 4 + r) * YS + lr] = acc[r];
        }
    } else {
        int t = (blockIdx.x - YB) * 256 + tid;   // t < 1152*128
        int kk = t >> 7;
        int o = t & 127;
        int ctt = kk / 144;
        int rem = kk - ctt * 144;
        int m = rem >> 4;
        int ci = rem & 15;
        float v = W[m * 16384 + o * 128 + ctt * 16 + ci];
        Wg[((kk >> 5) * 128 + o) * 32 + (kk & 31)] = __float2bfloat16(v);
    }
}

// ---------------- Kernel 2: fused (512 thr, 2 blocks/CU, pipelined) ----------
// LDS 69,632 B: S' [0,36864) (16 x 2304, kk'=ct*144+m*16+ci, XOR-swz (n&7)<<4);
// staging [36864, +8*4096): per-wave 4-slot x 1KB ring (q overlays slots 0-1).
// 8 waves x 2 nodes. Phase A barrier-free, tr-reads software-pipelined one slot
// ahead (counted lgkmcnt(2): only the 2 trailing S' b64 writes outstanding);
// gl_lds counted-vmcnt ring. Tail vmcnt = 2/1/0 (R4 bug: 3/2/1 raced the
// refill gl_lds of slots 1-3 against their tr-reads). One __syncthreads;
// phase B: all 8 waves, 16 rows, wave = col-tile.
template<bool BF16G>
__global__ __launch_bounds__(512, 4) void fused_kernel(const float* __restrict__ x,
                                                       const __hip_bfloat16* __restrict__ xb,
                                                       const int* __restrict__ adj,
                                                       const float* __restrict__ y,
                                                       const float* __restrict__ cv,
                                                       const __hip_bfloat16* __restrict__ Wg,
                                                       const float* __restrict__ bv,
                                                       float* __restrict__ out) {
    __shared__ __align__(16) char smem[SMEMB];

    int tid = threadIdx.x;
    int lane = tid & 63, wv = tid >> 6;              // 8 waves
    int lr = lane & 15, quad = lane >> 4;
    int node0 = blockIdx.x * NPB;
    int b = node0 / NN;
    int n0 = node0 - b * NN;

    // ---- A1: softmax lanes (lane<32): lanes[0,16)=node 2wv, [16,32)=2wv+1 ----
    bool sm = (lane < 32);
    int lnode = wv * 2 + (quad & 1);                 // valid when sm
    int a = 0;
    if (sm) a = adj[(n0 + lnode) * NKN + lr];
    int rowint = b * NN + ((a > 0) ? a - 1 : 0);

    float4 yn0 = {0,0,0,0}, yn1 = {0,0,0,0}, ya0 = {0,0,0,0}, ya1 = {0,0,0,0};
    float yn8 = 0.f, ya8 = 0.f;
    if (sm) {
        const float* yn = y + (long)(node0 + lnode) * YS;
        const float* ya = y + (long)rowint * YS;
        yn0 = *(const float4*)yn;  yn1 = *(const float4*)(yn + 4);  yn8 = yn[8];
        ya0 = *(const float4*)ya;  ya1 = *(const float4*)(ya + 4);  ya8 = ya[8];
    }

    unsigned long long mk = __ballot(a > 0);
    int d = (int)__popcll((mk >> (quad * 16)) & 0xFFFFull);
    float di = (d > 0) ? 1.f / (float)d : 0.f;

    // ---- gather lane mapping: slot byte pos*16 = kq*128 + j*32 + h*16 ----
    int pos = lane & 31;
    int e   = ((pos >> 3) << 2) | ((pos >> 1) & 3); // edge this lane fetches
    int hh  = pos & 1;                              // 16B half within 32B ct chunk
    int ctl = lane >> 5;                            // ct-local within 1KB pair-slot
    int rowA = __shfl(rowint, e);                   // node 2wv, edge e row
    int rowB = __shfl(rowint, 16 + e);              // node 2wv+1

    unsigned wboff = PBASE + (unsigned)(wv * 4096);
    unsigned sb = (unsigned)(uintptr_t)&smem[0];
    unsigned wba = sb + wboff;

    // ---- A2: softmax; q' = softmax * deg_inv, dual-bf16 hi/lo ----
    if (sm) {
        float sel = (a > 0) ? 1.f : 0.f;
        float l[NM];
        l[0] = yn0.x - sel * ya0.x + cv[0];
        l[1] = yn0.y - sel * ya0.y + cv[1];
        l[2] = yn0.z - sel * ya0.z + cv[2];
        l[3] = yn0.w - sel * ya0.w + cv[3];
        l[4] = yn1.x - sel * ya1.x + cv[4];
        l[5] = yn1.y - sel * ya1.y + cv[5];
        l[6] = yn1.z - sel * ya1.z + cv[6];
        l[7] = yn1.w - sel * ya1.w + cv[7];
        l[8] = yn8   - sel * ya8   + cv[8];
        float mx = l[0];
        #pragma unroll
        for (int m = 1; m < NM; m++) mx = fmaxf(mx, l[m]);
        float e_[NM]; float sum = 0.f;
        #pragma unroll
        for (int m = 0; m < NM; m++) { e_[m] = expf(l[m] - mx); sum += e_[m]; }
        float qf = ((a > 0) ? (1.f / sum) : 0.f) * di;

        union { u16x8 v[2]; unsigned short s[16]; } H, L;
        #pragma unroll
        for (int m = 0; m < NM; m++) {
            float qv = e_[m] * qf;
            unsigned short hb = bfb(qv);
            union { unsigned short u; __hip_bfloat16 bb; } hv; hv.u = hb;
            H.s[m] = hb;
            L.s[m] = bfb(qv - __bfloat162float(hv.bb));
        }
        #pragma unroll
        for (int m = NM; m < 16; m++) { H.s[m] = 0; L.s[m] = 0; }

        // node nn=(quad&1) q tile at wboff + nn*1024 (overlays P slots 0-1)
        unsigned qo = wboff + (unsigned)((quad & 1) * 1024 +
                                         (lr >> 2) * 128 + (lr & 3) * 32);
        *(u16x8*)(smem + qo)       = H.v[0];
        *(u16x8*)(smem + qo + 16)  = H.v[1];
        *(u16x8*)(smem + qo + 512) = L.v[0];
        *(u16x8*)(smem + qo + 528) = L.v[1];
    }
    asm volatile("s_waitcnt lgkmcnt(0)" ::: "memory");
    __builtin_amdgcn_sched_barrier(0);

    // ---- q frags (B-operand of swapped MFMA), verified addressing ----
    bf16x4 qa0, qa1, qb0, qb1;
    unsigned qra = wba + (unsigned)(quad * 256 + lr * 8);
    asm volatile("ds_read_b64_tr_b16 %0, %2 offset:0\n\t"
                 "ds_read_b64_tr_b16 %1, %2 offset:128"
                 : "=&v"(qa0), "=&v"(qa1) : "v"(qra));
    asm volatile("ds_read_b64_tr_b16 %0, %2 offset:1024\n\t"
                 "ds_read_b64_tr_b16 %1, %2 offset:1152"
                 : "=&v"(qb0), "=&v"(qb1) : "v"(qra));
    asm volatile("s_waitcnt lgkmcnt(0)" ::: "memory");
    __builtin_amdgcn_sched_barrier(0);
    frg8 fragA, fragB;
    fragA.h[0] = qa0; fragA.h[1] = qa1;
    fragB.h[0] = qb0; fragB.h[1] = qb1;

    // slot S (0..7): node nn=S>>2, ct-pair t=S&3; ring slot S&3 (1KB)
    #define ISSUE(S) {                                                          \
        long rr = (long)(((S) >> 2) ? rowB : rowA);                             \
        const __hip_bfloat16* gp = xb + rr * NC +                               \
                                   (2 * ((S) & 3) + ctl) * 16 + hh * 8;         \
        __builtin_amdgcn_global_load_lds((gas_void*)gp,                         \
            (las_void*)(smem + wboff + (unsigned)(((S) & 3) * 1024)), 16, 0, 0);\
    }

    #define TRREAD(D0, D1, D2, D3, SLOT) {                                      \
        unsigned pr_ = wba + (unsigned)((SLOT) * 1024 + (quad & 1) * 256 +      \
                                        lr * 8);                                \
        asm volatile("ds_read_b64_tr_b16 %0, %4 offset:0\n\t"                   \
                     "ds_read_b64_tr_b16 %1, %4 offset:128\n\t"                 \
                     "ds_read_b64_tr_b16 %2, %4 offset:512\n\t"                 \
                     "ds_read_b64_tr_b16 %3, %4 offset:640"                     \
                     : "=&v"(D0), "=&v"(D1), "=&v"(D2), "=&v"(D3)               \
                     : "v"(pr_));                                               \
    }

    #define MFMA_STORE(S, F0, F1, F2, F3) {                                     \
        int nl_ = 2 * wv + ((S) >> 2);                                          \
        unsigned swz_ = (unsigned)((nl_ & 7) << 4);                             \
        f32x4 z = (f32x4){0.f, 0.f, 0.f, 0.f};                                  \
        frg8 pf; pf.h[0] = F0; pf.h[1] = F1;                                    \
        f32x4 ac = __builtin_amdgcn_mfma_f32_16x16x32_bf16(pf.v,                \
                       ((S) >> 2) ? fragB.v : fragA.v, z, 0, 0, 0);             \
        bf16x4 sv;                                                              \
        sv[0] = (short)bfb(ac[0]); sv[1] = (short)bfb(ac[1]);                   \
        sv[2] = (short)bfb(ac[2]); sv[3] = (short)bfb(ac[3]);                   \
        unsigned so = ((unsigned)((2 * ((S) & 3)) * 288 + lr * 32 +             \
                                  quad * 8)) ^ swz_;                            \
        if (lr < 9) *(bf16x4*)(smem + nl_ * SROW + so) = sv;                    \
        pf.h[0] = F2; pf.h[1] = F3;                                             \
        ac = __builtin_amdgcn_mfma_f32_16x16x32_bf16(pf.v,                      \
                 ((S) >> 2) ? fragB.v : fragA.v, z, 0, 0, 0);                   \
        sv[0] = (short)bfb(ac[0]); sv[1] = (short)bfb(ac[1]);                   \
        sv[2] = (short)bfb(ac[2]); sv[3] = (short)bfb(ac[3]);                   \
        so = ((unsigned)((2 * ((S) & 3) + 1) * 288 + lr * 32 +                  \
                         quad * 8)) ^ swz_;                                     \
        if (lr < 9) *(bf16x4*)(smem + nl_ * SROW + so) = sv;                    \
    }

    if (BF16G) {
        // ITER(S): wait tr_reads(S) done (2 trailing S' writes may remain);
        // refill ring slot; wait load(S+1) landed (counted); issue tr_reads(S+1);
        // MFMA+store S.
        // vmem queue replay (gl_lds only): prologue [0,1,2,3]; ITER S<4 pushes
        // S+4. TRREAD(S+1) needs ISSUE(S+1) landed:
        //   ITER0-3: queue 4 deep -> vmcnt(3). ITER4: [5,6,7] need 5 -> vmcnt(2).
        //   ITER5: need 6 -> vmcnt(1). ITER6: need 7 -> vmcnt(0). ITER7: none.
        #define ITER(S, LKS, VWS, C0, C1, C2, C3, N0, N1, N2, N3, DOV) {        \
            asm volatile("s_waitcnt lgkmcnt(" LKS ")" ::: "memory");            \
            __builtin_amdgcn_sched_barrier(0);                                  \
            if ((S) < 4) { ISSUE((S) + 4) }                                     \
            if (DOV) {                                                          \
                asm volatile("s_waitcnt vmcnt(" VWS ")" ::: "memory");          \
                __builtin_amdgcn_sched_barrier(0);                              \
                TRREAD(N0, N1, N2, N3, ((S) + 1) & 3)                           \
            }                                                                   \
            MFMA_STORE(S, C0, C1, C2, C3)                                       \
        }

        asm volatile("s_waitcnt vmcnt(0)" ::: "memory");   // clean baseline
        __builtin_amdgcn_sched_barrier(0);
        ISSUE(0) ISSUE(1) ISSUE(2) ISSUE(3)
        asm volatile("s_waitcnt vmcnt(3)" ::: "memory");   // slot 0 landed
        __builtin_amdgcn_sched_barrier(0);
        bf16x4 cf0, cf1, cf2, cf3, nf0, nf1, nf2, nf3;
        TRREAD(cf0, cf1, cf2, cf3, 0)

        ITER(0, "0", "3", cf0, cf1, cf2, cf3, nf0, nf1, nf2, nf3, 1)
        ITER(1, "2", "3", nf0, nf1, nf2, nf3, cf0, cf1, cf2, cf3, 1)
        ITER(2, "2", "3", cf0, cf1, cf2, cf3, nf0, nf1, nf2, nf3, 1)
        ITER(3, "2", "3", nf0, nf1, nf2, nf3, cf0, cf1, cf2, cf3, 1)
        ITER(4, "2", "2", cf0, cf1, cf2, cf3, nf0, nf1, nf2, nf3, 1)
        ITER(5, "2", "1", nf0, nf1, nf2, nf3, cf0, cf1, cf2, cf3, 1)
        ITER(6, "2", "0", cf0, cf1, cf2, cf3, nf0, nf1, nf2, nf3, 1)
        ITER(7, "2", "0", nf0, nf1, nf2, nf3, cf0, cf1, cf2, cf3, 0)
        #undef ITER
    } else {
        #pragma unroll
        for (int S = 0; S < 8; ++S) {
            long rr_ = (long)((S >= 4) ? rowB : rowA);
            const float* fp = x + rr_ * NC + (2 * (S & 3) + ctl) * 16 + hh * 8;
            float4 f0 = *(const float4*)fp;
            float4 f1 = *(const float4*)(fp + 4);
            union { u16x8 v; unsigned short s[8]; } ov;
            ov.s[0] = bfb(f0.x); ov.s[1] = bfb(f0.y); ov.s[2] = bfb(f0.z);
            ov.s[3] = bfb(f0.w); ov.s[4] = bfb(f1.x); ov.s[5] = bfb(f1.y);
            ov.s[6] = bfb(f1.z); ov.s[7] = bfb(f1.w);
            *(u16x8*)(smem + wboff + (unsigned)((S & 3) * 1024 + lane * 16)) = ov.v;
            asm volatile("s_waitcnt lgkmcnt(0)" ::: "memory");
            __builtin_amdgcn_sched_barrier(0);
            bf16x4 e0, e1, e2, e3;
            TRREAD(e0, e1, e2, e3, S & 3)
            asm volatile("s_waitcnt lgkmcnt(0)" ::: "memory");
            __builtin_amdgcn_sched_barrier(0);
            MFMA_STORE(S, e0, e1, e2, e3)
        }
    }
    #undef MFMA_STORE
    #undef TRREAD
    #undef ISSUE

    __syncthreads();                                   // S' ready block-wide
    __builtin_amdgcn_sched_barrier(0);

    // ---- phase B: all 8 waves, 16x1152 @ 1152x128; wave = col-tile ----
    {
        const short* wg = reinterpret_cast<const short*>(Wg);
        f32x4 acc0 = (f32x4){0.f, 0.f, 0.f, 0.f};
        unsigned swzB = (unsigned)((lr & 7) << 4);
        #pragma unroll 9
        for (int kc = 0; kc < 36; kc++) {
            bf16x8 bfrag = *(const bf16x8*)(wg + ((kc * 128) + wv * 16 + lr) * 32
                                            + quad * 8);
            unsigned ao = ((unsigned)(kc * 64 + quad * 16)) ^ swzB;
            bf16x8 a0 = *(const bf16x8*)(smem + (unsigned)(lr * SROW) + ao);
            acc0 = __builtin_amdgcn_mfma_f32_16x16x32_bf16(a0, bfrag, acc0, 0, 0, 0);
        }

        int col = wv * 16 + lr;
        float bb = bv[col];
        int rbase = node0 + quad * 4;
        #pragma unroll
        for (int r = 0; r < 4; r++)
            out[(long)(rbase + r) * NO + col] = acc0[r] + bb;
    }
}

extern "C" void kernel_launch(void* const* d_in, const int* in_sizes, int n_in,
                              void* d_out, int out_size, void* d_ws, size_t ws_size,
                              hipStream_t stream) {
    const float* x   = (const float*)d_in[0];   // (B,N,C)
    const int*   adj = (const int*)  d_in[1];   // (N,K)
    const float* W   = (const float*)d_in[2];   // (M,O,C)
    const float* bv  = (const float*)d_in[3];   // (O,)
    const float* u   = (const float*)d_in[4];   // (M,C)
    const float* cv  = (const float*)d_in[5];   // (M,)
    float* out = (float*)d_out;

    char* ws = (char*)d_ws;
    float* y = (float*)ws;                                     // 1,920,000 B
    __hip_bfloat16* Wg = (__hip_bfloat16*)(ws + 1920000);      //   294,912 B
    __hip_bfloat16* xb = (__hip_bfloat16*)(ws + 2214912);      // 10,240,000 B
    bool use_xb = (ws_size >= (size_t)12454912);

    prep_kernel<<<YB + 576, 256, 0, stream>>>(x, u, W, y, use_xb ? xb : nullptr, Wg,
                                              use_xb ? 1 : 0);
    if (use_xb)
        fused_kernel<true><<<NR / NPB, 512, 0, stream>>>(x, xb, adj, y, cv, Wg, bv, out);
    else
        fused_kernel<false><<<NR / NPB, 512, 0, stream>>>(x, xb, adj, y, cv, Wg, bv, out);
}

// Round 7
// 134.269 us; speedup vs baseline: 1.1205x; 1.1205x over previous
//
#include <hip/hip_runtime.h>
#include <hip/hip_bf16.h>

#define NB 2
#define NN 20000
#define NKN 16          // neighbors per node
#define NC 128          // C_IN
#define NM 9            // M kernels
#define NO 128          // C_OUT
#define NR (NB*NN)      // 40000 rows
#define KK (NM*NC)      // 1152 GEMM reduce dim
#define NKC (KK/32)     // 36 K-chunks of 32
#define NPB 32          // nodes per fused block (20000 % 32 == 0 -> no batch straddle)
#define YS 12           // padded y row stride (floats) -> float4-aligned
#define QS (NKN*12+4)   // per-node q stride (floats): ≡4 mod 32 banks -> conflict-free
#define YB (NR/64)      // ycalc blocks (64 nodes each) = 625

typedef short bf16x8 __attribute__((ext_vector_type(8)));
typedef float f32x4 __attribute__((ext_vector_type(4)));
typedef float f32x2 __attribute__((ext_vector_type(2)));
typedef unsigned short u16x8 __attribute__((ext_vector_type(8)));

__device__ inline f32x2 bfpair(unsigned int w) {   // [lo16, hi16] bf16 -> float2
    union { unsigned int u; float f; } lo, hi;
    lo.u = w << 16; hi.u = w & 0xFFFF0000u;
    return (f32x2){lo.f, hi.f};
}

// ---------------- Kernel 1: prep (R0 version, original Wg K-order) ----------------
__global__ __launch_bounds__(256) void prep_kernel(const float* __restrict__ x,
                                                   const float* __restrict__ u,
                                                   const float* __restrict__ W,
                                                   float* __restrict__ y,
                                                   __hip_bfloat16* __restrict__ xb,
                                                   __hip_bfloat16* __restrict__ Wg,
                                                   int use_xb) {
    int tid = threadIdx.x;
    if (blockIdx.x < YB) {
        int wave = tid >> 6, lane = tid & 63;
        int lr = lane & 15, quad = lane >> 4;
        int node0 = blockIdx.x * 64 + wave * 16;
        long xbase = (long)(node0 + lr) * NC;

        bf16x8 afr[4];
        #pragma unroll
        for (int kc = 0; kc < 4; kc++) {
            const float* px = x + xbase + kc * 32 + quad * 8;
            float4 a0 = *(const float4*)px;
            float4 a1 = *(const float4*)(px + 4);
            union { bf16x8 v; unsigned short s[8]; __hip_bfloat16 h[8]; } af;
            af.h[0] = __float2bfloat16(a0.x); af.h[1] = __float2bfloat16(a0.y);
            af.h[2] = __float2bfloat16(a0.z); af.h[3] = __float2bfloat16(a0.w);
            af.h[4] = __float2bfloat16(a1.x); af.h[5] = __float2bfloat16(a1.y);
            af.h[6] = __float2bfloat16(a1.z); af.h[7] = __float2bfloat16(a1.w);
            afr[kc] = af.v;
            if (use_xb)
                *(u16x8*)((unsigned short*)xb + xbase + kc * 32 + quad * 8) =
                    *(u16x8*)&af.v;
        }
        int cs = (lr < NM) ? lr : 0;
        float fz = (lr < NM) ? 1.f : 0.f;
        f32x4 acc = (f32x4){0.f, 0.f, 0.f, 0.f};
        #pragma unroll
        for (int kc = 0; kc < 4; kc++) {
            const float* pu = u + cs * NC + kc * 32 + quad * 8;
            float4 b0 = *(const float4*)pu;
            float4 b1 = *(const float4*)(pu + 4);
            union { bf16x8 v; __hip_bfloat16 h[8]; } bf;
            bf.h[0] = __float2bfloat16(b0.x * fz); bf.h[1] = __float2bfloat16(b0.y * fz);
            bf.h[2] = __float2bfloat16(b0.z * fz); bf.h[3] = __float2bfloat16(b0.w * fz);
            bf.h[4] = __float2bfloat16(b1.x * fz); bf.h[5] = __float2bfloat16(b1.y * fz);
            bf.h[6] = __float2bfloat16(b1.z * fz); bf.h[7] = __float2bfloat16(b1.w * fz);
            acc = __builtin_amdgcn_mfma_f32_16x16x32_bf16(afr[kc], bf.v, acc, 0, 0, 0);
        }
        if (lr < NM) {
            #pragma unroll
            for (int r = 0; r < 4; r++)
                y[(long)(node0 + quad * 4 + r) * YS + lr] = acc[r];
        }
    } else {
        int t = (blockIdx.x - YB) * 256 + tid;   // t < 1152*128
        int kk = t >> 7;
        int o = t & 127;
        int m = kk >> 7;
        int c = kk & 127;
        float v = W[m * 16384 + o * 128 + c];
        Wg[((kk >> 5) * 128 + o) * 32 + (kk & 31)] = __float2bfloat16(v);
    }
}

// ---------------- Kernel 2: fused (R0 datapath, 2 barriers removed) ----------
// Block = 32 nodes, 512 threads, 73,728 B LDS -> 2 blocks/CU.
// Delta vs R0 (57.3 µs):
//  - bar1 removed: adj row loaded per-thread as 4x int4 (L1-broadcast within
//    the node's 16 threads); idx/deg from registers; gathers issue earlier.
//  - bar2 removed: a node's 16 threads are within ONE wave (tid [16ln,16ln+16)),
//    so the q LDS exchange is intra-wave -> lgkmcnt(0) fence suffices
//    (wave lockstep: all lanes' ds_writes precede the fence in program order).
//  - bar2.5/bar3 kept: S' region is consumed cross-wave in phase B.
// s_q overlay now starts at smem+0 (s_adj eliminated).
template<bool BF16G>
__global__ __launch_bounds__(512, 4) void fused_kernel(const float* __restrict__ x,
                                                       const __hip_bfloat16* __restrict__ xb,
                                                       const int* __restrict__ adj,
                                                       const float* __restrict__ y,
                                                       const float* __restrict__ cv,
                                                       const __hip_bfloat16* __restrict__ Wg,
                                                       const float* __restrict__ bv,
                                                       float* __restrict__ out) {
    __shared__ __align__(16) short s_S[NPB * KK];          // 73,728 B total LDS
    float* s_q = (float*)s_S;                              // [NPB*QS] = 25,088 B overlay

    int tid = threadIdx.x;
    int node0 = blockIdx.x * NPB;
    int b = node0 / NN;
    int n0 = node0 - b * NN;
    int ln = tid >> 4, k = tid & 15;                       // 512 = 32 nodes x 16 edges

    // ---- A1: own edge + full adj row (no LDS, no barrier) ----
    const int* arow = adj + (n0 + ln) * NKN;
    int a = arow[k];                                       // own edge (L1 hit)
    int4 r0 = *(const int4*)arow;
    int4 r1 = *(const int4*)(arow + 4);
    int4 r2 = *(const int4*)(arow + 8);
    int4 r3 = *(const int4*)(arow + 12);

    const float* yn = y + (long)(node0 + ln) * YS;
    const float* ya = y + (long)(b * NN + ((a > 0) ? a - 1 : 0)) * YS;
    float4 yn0 = *(const float4*)yn;
    float4 yn1 = *(const float4*)(yn + 4);
    float  yn8 = yn[8];
    float4 ya0 = *(const float4*)ya;
    float4 ya1 = *(const float4*)(ya + 4);
    float  ya8 = ya[8];

    // ---- idx/deg from registers (static indexing); issue gather batch 0 ----
    int idx[NKN]; int d = 0;
    #define PUT(J, V) { int aa = (V); d += (aa > 0); idx[J] = (aa > 0) ? aa - 1 : 0; }
    PUT(0, r0.x)  PUT(1, r0.y)  PUT(2, r0.z)  PUT(3, r0.w)
    PUT(4, r1.x)  PUT(5, r1.y)  PUT(6, r1.z)  PUT(7, r1.w)
    PUT(8, r2.x)  PUT(9, r2.y)  PUT(10, r2.z) PUT(11, r2.w)
    PUT(12, r3.x) PUT(13, r3.y) PUT(14, r3.z) PUT(15, r3.w)
    #undef PUT
    float di = (d > 0) ? 1.f / (float)d : 0.f;

    int c8 = k << 3;
    uint4 pw0[8];
    if (BF16G) {
        #pragma unroll
        for (int j = 0; j < 8; j++)
            pw0[j] = *(const uint4*)((const unsigned short*)xb +
                                     (long)(b * NN + idx[j]) * NC + c8);
    }

    // ---- A2: softmax on pre-loaded y; q pre-zeroed for padding edges ----
    {
        float sel = (a > 0) ? 1.f : 0.f;
        float l[NM];
        l[0] = yn0.x - sel * ya0.x + cv[0];
        l[1] = yn0.y - sel * ya0.y + cv[1];
        l[2] = yn0.z - sel * ya0.z + cv[2];
        l[3] = yn0.w - sel * ya0.w + cv[3];
        l[4] = yn1.x - sel * ya1.x + cv[4];
        l[5] = yn1.y - sel * ya1.y + cv[5];
        l[6] = yn1.z - sel * ya1.z + cv[6];
        l[7] = yn1.w - sel * ya1.w + cv[7];
        l[8] = yn8   - sel * ya8   + cv[8];
        float mx = l[0];
        #pragma unroll
        for (int m = 1; m < NM; m++) mx = fmaxf(mx, l[m]);
        float e[NM]; float sum = 0.f;
        #pragma unroll
        for (int m = 0; m < NM; m++) { e[m] = expf(l[m] - mx); sum += e[m]; }
        float qs = (a > 0) ? (1.f / sum) : 0.f;
        #pragma unroll
        for (int m = 0; m < NM; m++) s_q[ln * QS + k * 12 + m] = e[m] * qs;
    }
    // intra-wave q exchange: producers/consumers of node ln share one wave.
    asm volatile("s_waitcnt lgkmcnt(0)" ::: "memory");
    __builtin_amdgcn_sched_barrier(0);

    // ---- A3: issue batch 1, then accumulate both batches (f32x2 packed FMA) ----
    f32x2 s2[NM][4];
    #pragma unroll
    for (int m = 0; m < NM; m++)
        #pragma unroll
        for (int j = 0; j < 4; j++) s2[m][j] = (f32x2){0.f, 0.f};

    #define ACC_ALL(P0, P1, P2, P3, KK2) {                                    \
        const float* qr = &s_q[ln * QS + (KK2) * 12];                         \
        float4 qa = *(const float4*)qr;                                       \
        float4 qb = *(const float4*)(qr + 4);                                 \
        float  q8 = qr[8];                                                    \
        f32x2 qq;                                                             \
        qq=(f32x2){qa.x,qa.x}; s2[0][0]+=qq*P0; s2[0][1]+=qq*P1; s2[0][2]+=qq*P2; s2[0][3]+=qq*P3; \
        qq=(f32x2){qa.y,qa.y}; s2[1][0]+=qq*P0; s2[1][1]+=qq*P1; s2[1][2]+=qq*P2; s2[1][3]+=qq*P3; \
        qq=(f32x2){qa.z,qa.z}; s2[2][0]+=qq*P0; s2[2][1]+=qq*P1; s2[2][2]+=qq*P2; s2[2][3]+=qq*P3; \
        qq=(f32x2){qa.w,qa.w}; s2[3][0]+=qq*P0; s2[3][1]+=qq*P1; s2[3][2]+=qq*P2; s2[3][3]+=qq*P3; \
        qq=(f32x2){qb.x,qb.x}; s2[4][0]+=qq*P0; s2[4][1]+=qq*P1; s2[4][2]+=qq*P2; s2[4][3]+=qq*P3; \
        qq=(f32x2){qb.y,qb.y}; s2[5][0]+=qq*P0; s2[5][1]+=qq*P1; s2[5][2]+=qq*P2; s2[5][3]+=qq*P3; \
        qq=(f32x2){qb.z,qb.z}; s2[6][0]+=qq*P0; s2[6][1]+=qq*P1; s2[6][2]+=qq*P2; s2[6][3]+=qq*P3; \
        qq=(f32x2){qb.w,qb.w}; s2[7][0]+=qq*P0; s2[7][1]+=qq*P1; s2[7][2]+=qq*P2; s2[7][3]+=qq*P3; \
        qq=(f32x2){q8,q8};     s2[8][0]+=qq*P0; s2[8][1]+=qq*P1; s2[8][2]+=qq*P2; s2[8][3]+=qq*P3; }

    if (BF16G) {
        uint4 pw1[8];
        #pragma unroll
        for (int j = 0; j < 8; j++)
            pw1[j] = *(const uint4*)((const unsigned short*)xb +
                                     (long)(b * NN + idx[8 + j]) * NC + c8);
        #pragma unroll
        for (int j = 0; j < 8; j++) {
            f32x2 p0 = bfpair(pw0[j].x), p1 = bfpair(pw0[j].y);
            f32x2 p2 = bfpair(pw0[j].z), p3 = bfpair(pw0[j].w);
            ACC_ALL(p0, p1, p2, p3, j)
        }
        #pragma unroll
        for (int j = 0; j < 8; j++) {
            f32x2 p0 = bfpair(pw1[j].x), p1 = bfpair(pw1[j].y);
            f32x2 p2 = bfpair(pw1[j].z), p3 = bfpair(pw1[j].w);
            ACC_ALL(p0, p1, p2, p3, 8 + j)
        }
    } else {
        #pragma unroll
        for (int g = 0; g < NKN / 4; g++) {
            float4 fa[4], fb[4];
            #pragma unroll
            for (int j = 0; j < 4; j++) {
                const float* px = x + (long)(b * NN + idx[g * 4 + j]) * NC + c8;
                fa[j] = *(const float4*)px;
                fb[j] = *(const float4*)(px + 4);
            }
            #pragma unroll
            for (int j = 0; j < 4; j++) {
                f32x2 p0 = (f32x2){fa[j].x, fa[j].y}, p1 = (f32x2){fa[j].z, fa[j].w};
                f32x2 p2 = (f32x2){fb[j].x, fb[j].y}, p3 = (f32x2){fb[j].z, fb[j].w};
                ACC_ALL(p0, p1, p2, p3, g * 4 + j)
            }
        }
    }
    #undef ACC_ALL
    __syncthreads();                                       // bar2.5: q now dead

    // ---- pack + write S' into (now-free) s_S, XOR-swizzled ----
    #pragma unroll
    for (int m = 0; m < NM; m++) {
        u16x8 ov;
        #pragma unroll
        for (int j = 0; j < 4; j++) {
            union { unsigned short h; __hip_bfloat16 bb; } c0, c1;
            c0.bb = __float2bfloat16(s2[m][j][0] * di);
            c1.bb = __float2bfloat16(s2[m][j][1] * di);
            ov[j * 2]     = c0.h;
            ov[j * 2 + 1] = c1.h;
        }
        int g = m * 16 + k;                                // 16B granule index in row
        int gs = g ^ (ln & 7);                             // XOR swizzle
        *(u16x8*)(&s_S[ln * KK + gs * 8]) = ov;
    }
    __syncthreads();                                       // bar3: S' ready

    // -------- phase B: GEMM 32x1152 @ 1152x128; wave = col-tile x 2 row-tiles -------
    int wave = tid >> 6;                                   // col-tile 0..7
    int lane = tid & 63;
    int lr = lane & 15;
    int quad = lane >> 4;
    const short* wg = reinterpret_cast<const short*>(Wg);
    f32x4 acc0 = (f32x4){0.f, 0.f, 0.f, 0.f};              // rows 0..15
    f32x4 acc1 = (f32x4){0.f, 0.f, 0.f, 0.f};              // rows 16..31

    #pragma unroll 9
    for (int kc = 0; kc < NKC; kc++) {
        int g = kc * 4 + quad;
        int gs = g ^ (lr & 7);                             // (16+lr)&7 == lr&7
        bf16x8 bfrag = *(const bf16x8*)(wg + ((kc * 128) + wave * 16 + lr) * 32 + quad * 8);
        bf16x8 a0 = *(const bf16x8*)(&s_S[lr * KK + gs * 8]);
        bf16x8 a1 = *(const bf16x8*)(&s_S[(16 + lr) * KK + gs * 8]);
        acc0 = __builtin_amdgcn_mfma_f32_16x16x32_bf16(a0, bfrag, acc0, 0, 0, 0);
        acc1 = __builtin_amdgcn_mfma_f32_16x16x32_bf16(a1, bfrag, acc1, 0, 0, 0);
    }

    // epilogue: D row = quad*4 + r, col = wave*16 + lr
    int col = wave * 16 + lr;
    float bb = bv[col];
    int rbase = node0 + quad * 4;
    #pragma unroll
    for (int r = 0; r < 4; r++) {
        out[(long)(rbase + r) * NO + col]      = acc0[r] + bb;
        out[(long)(rbase + 16 + r) * NO + col] = acc1[r] + bb;
    }
}

extern "C" void kernel_launch(void* const* d_in, const int* in_sizes, int n_in,
                              void* d_out, int out_size, void* d_ws, size_t ws_size,
                              hipStream_t stream) {
    const float* x   = (const float*)d_in[0];   // (B,N,C)
    const int*   adj = (const int*)  d_in[1];   // (N,K)
    const float* W   = (const float*)d_in[2];   // (M,O,C)
    const float* bv  = (const float*)d_in[3];   // (O,)
    const float* u   = (const float*)d_in[4];   // (M,C)
    const float* cv  = (const float*)d_in[5];   // (M,)
    float* out = (float*)d_out;

    char* ws = (char*)d_ws;
    float* y = (float*)ws;                                     // 40000*12*4 = 1,920,000 B
    __hip_bfloat16* Wg = (__hip_bfloat16*)(ws + 1920000);      //   294,912 B
    __hip_bfloat16* xb = (__hip_bfloat16*)(ws + 2214912);      // 10,240,000 B (16B-aligned)
    bool use_xb = (ws_size >= (size_t)12454912);

    prep_kernel<<<YB + 576, 256, 0, stream>>>(x, u, W, y, use_xb ? xb : nullptr, Wg,
                                              use_xb ? 1 : 0);
    if (use_xb)
        fused_kernel<true><<<NR / NPB, 512, 0, stream>>>(x, xb, adj, y, cv, Wg, bv, out);
    else
        fused_kernel<false><<<NR / NPB, 512, 0, stream>>>(x, xb, adj, y, cv, Wg, bv, out);
}